// Round 5
// baseline (196.035 us; speedup 1.0000x reference)
//
#include <hip/hip_runtime.h>

typedef __bf16 bf16;
typedef __attribute__((ext_vector_type(8))) __bf16 bf16x8;
typedef __attribute__((ext_vector_type(4))) __bf16 bf16x4;
typedef __attribute__((ext_vector_type(2))) __bf16 bf16x2;
typedef __attribute__((ext_vector_type(4))) float f32x4;

#define MFMA(a, b, c) __builtin_amdgcn_mfma_f32_16x16x32_bf16((a), (b), (c), 0, 0, 0)
#define LOG2E 1.44269504088896340736f

__device__ __forceinline__ bf16x8 cvt8(float4 a, float4 b) {
  bf16x8 r;
  r[0] = (bf16)a.x; r[1] = (bf16)a.y; r[2] = (bf16)a.z; r[3] = (bf16)a.w;
  r[4] = (bf16)b.x; r[5] = (bf16)b.y; r[6] = (bf16)b.z; r[7] = (bf16)b.w;
  return r;
}

__device__ __forceinline__ int pk2(float x, float y) {
  union { bf16x2 h; int i; } u;
  u.h[0] = (bf16)x; u.h[1] = (bf16)y;
  return u.i;
}

// async global->LDS, 16B per lane. LDS dest = wave-uniform base + lane*16.
__device__ __forceinline__ void stage16(const bf16* g, bf16* l) {
  __builtin_amdgcn_global_load_lds(
      (const __attribute__((address_space(1))) void*)g,
      (__attribute__((address_space(3))) void*)l, 16, 0, 0);
}

// ---------------------------------------------------------------------------
// Kernel 0: cast X -> bf16; cast+transpose W -> bf16 W^T[n][k] (3 matrices).
// ---------------------------------------------------------------------------
__global__ __launch_bounds__(256)
void cvt(const float* __restrict__ hs, const float* __restrict__ qw,
         const float* __restrict__ kw, const float* __restrict__ vw,
         bf16* __restrict__ Xb, bf16* __restrict__ Wt) {
  const int bid = blockIdx.x, tid = threadIdx.x;
  if (bid < 2048) {               // X: 4096x1024 fp32 -> bf16, 8 elems/thread
    size_t off = (size_t)bid * 2048 + tid * 8;
    float4 x0 = *(const float4*)(hs + off);
    float4 x1 = *(const float4*)(hs + off + 4);
    *(bf16x8*)(Xb + off) = cvt8(x0, x1);
  } else {                        // W transpose: 64x64 tiles via LDS
    int t = bid - 2048;           // 0..767
    int z = t >> 8, ti = t & 255;
    const float* W = (z == 0) ? qw : (z == 1) ? kw : vw;
    int k0 = (ti >> 4) * 64, n0 = (ti & 15) * 64;
    __shared__ bf16 T[64 * 72];   // [n][k], pad 72
    #pragma unroll
    for (int i = 0; i < 16; ++i) {
      int e = i * 256 + tid;
      int kr = e >> 6, nc = e & 63;
      T[nc * 72 + kr] = (bf16)W[(size_t)(k0 + kr) * 1024 + n0 + nc];
    }
    __syncthreads();
    #pragma unroll
    for (int i = 0; i < 2; ++i) {
      int e = i * 256 + tid;
      int nr = e >> 3, kg = e & 7;
      *(bf16x8*)(Wt + (size_t)z * 1048576 + (size_t)(n0 + nr) * 1024 + k0 + kg * 8) =
          *(const bf16x8*)&T[nr * 72 + kg * 8];
    }
  }
}

// ---------------------------------------------------------------------------
// Kernel 1: QKV GEMM — m97 shape: 128x128 tile, 4 waves 2x2, BK=32,
// global_load_lds w=16, granule-XOR swizzle on the global-address side.
// VGPR ~164 -> 3 blocks/CU without spill. 768 blocks = one clean round.
// XCD swizzle: mb-band per XCD. Q pre-scaled by 0.125*log2e. V stored ^T.
// ---------------------------------------------------------------------------
__global__ __launch_bounds__(256, 3)
void qkv_gemm(const bf16* __restrict__ Xb, const bf16* __restrict__ Wt,
              const float* __restrict__ qbias, const float* __restrict__ kbias,
              const float* __restrict__ vbias,
              bf16* __restrict__ qo, bf16* __restrict__ ko, bf16* __restrict__ vo) {
  const int blk = blockIdx.x;                 // 0..767
  const int xcd = blk & 7, slot = blk >> 3;   // slot 0..95
  const int mb = xcd * 4 + slot / 24;         // 0..31
  const int nb = slot % 24;                   // 0..23
  const int z = nb >> 3, nbm = nb & 7;
  const bf16* W = Wt + (size_t)z * 1048576;

  const int tid = threadIdx.x;
  const int wave = tid >> 6, lane = tid & 63, quad = lane >> 4, c = lane & 15;
  const int wr = wave >> 1, wc = wave & 1;
  const int r4 = lane >> 2;                   // 0..15: row within 16-row group
  const int g4 = (lane & 3) ^ (r4 & 3);       // swizzled source granule (4/row)

  __shared__ bf16 As[128 * 32];               // [m][k], granule g stored at g^(m&3)
  __shared__ bf16 Bs[128 * 32];               // [n][k], same swizzle

  const bf16* aS0 = Xb + (size_t)(mb * 128 + wave * 16 + r4) * 1024 + g4 * 8;
  const bf16* aS1 = aS0 + (size_t)64 * 1024;
  const bf16* bS0 = W + (size_t)(nbm * 128 + wave * 16 + r4) * 1024 + g4 * 8;
  const bf16* bS1 = bS0 + (size_t)64 * 1024;
  bf16* aD0 = &As[(wave * 16) * 32];
  bf16* aD1 = &As[(64 + wave * 16) * 32];
  bf16* bD0 = &Bs[(wave * 16) * 32];
  bf16* bD1 = &Bs[(64 + wave * 16) * 32];

  int aOff[4], bOff[4];
  #pragma unroll
  for (int t = 0; t < 4; ++t) {
    aOff[t] = (wr * 64 + t * 16 + c) * 32 + ((quad ^ (c & 3)) << 3);
    bOff[t] = (wc * 64 + t * 16 + c) * 32 + ((quad ^ (c & 3)) << 3);
  }

  f32x4 acc[4][4] = {};

  for (int k0 = 0; k0 < 1024; k0 += 32) {
    stage16(aS0 + k0, aD0);
    stage16(aS1 + k0, aD1);
    stage16(bS0 + k0, bD0);
    stage16(bS1 + k0, bD1);
    __syncthreads();
    bf16x8 af[4];
    #pragma unroll
    for (int rt = 0; rt < 4; ++rt) af[rt] = *(const bf16x8*)&As[aOff[rt]];
    #pragma unroll
    for (int nt = 0; nt < 4; ++nt) {
      bf16x8 bfrag = *(const bf16x8*)&Bs[bOff[nt]];
      #pragma unroll
      for (int rt = 0; rt < 4; ++rt)
        acc[rt][nt] = MFMA(af[rt], bfrag, acc[rt][nt]);
    }
    __syncthreads();
  }

  const float* bias = (z == 0) ? qbias : (z == 1) ? kbias : vbias;
  float bv[4];
  #pragma unroll
  for (int nt = 0; nt < 4; ++nt)
    bv[nt] = bias[nbm * 128 + wc * 64 + nt * 16 + c];

  if (z == 2) {
    // V^T: vo[((b*16+h)*64 + d)*2048 + s], packed 4 along s (= reg dim)
    #pragma unroll
    for (int rt = 0; rt < 4; ++rt)
      #pragma unroll
      for (int nt = 0; nt < 4; ++nt) {
        int m0 = mb * 128 + wr * 64 + rt * 16 + 4 * quad;
        int n = nbm * 128 + wc * 64 + nt * 16 + c;
        bf16x4 pk;
        #pragma unroll
        for (int reg = 0; reg < 4; ++reg) pk[reg] = (bf16)(acc[rt][nt][reg] + bv[nt]);
        int b = m0 >> 11, s0 = m0 & 2047, h = n >> 6, d = n & 63;
        *(bf16x4*)&vo[(((size_t)b * 16 + h) * 64 + d) * 2048 + s0] = pk;
      }
  } else {
    bf16* dst = (z == 0) ? qo : ko;
    const float scale = (z == 0) ? 0.125f * LOG2E : 1.0f;
    #pragma unroll
    for (int rt = 0; rt < 4; ++rt)
      #pragma unroll
      for (int nt = 0; nt < 4; ++nt)
        #pragma unroll
        for (int reg = 0; reg < 4; ++reg) {
          float v = (acc[rt][nt][reg] + bv[nt]) * scale;
          int m = mb * 128 + wr * 64 + rt * 16 + 4 * quad + reg;
          int n = nbm * 128 + wc * 64 + nt * 16 + c;
          int b = m >> 11, s = m & 2047, h = n >> 6, d = n & 63;
          dst[(((size_t)b * 16 + h) * 2048 + s) * 64 + d] = (bf16)v;
        }
  }
}

// ---------------------------------------------------------------------------
// Kernel 2: attention. S^T via operand-swapped MFMA; P^T -> A-layout via a
// conflict-free 8-bpermute schedule (FIXED from R4):
//   src lane (qs,c) holds P keys {16nt+4qs+reg}, q=c, as pk[nt][reg>>1].
//   instr (tc,tp): every lane offers pk[tc ^ (quad&1)][tp]; dest pulls from
//   qs = 2(quad&1) + ((quad>>1)^(tc&1)); result = keys for A-slot
//   (ch=tc>>1, i = 2((quad>>1)^(tc&1)) + tp) -> slot pairs {0,1}/{2,3}
//   swap for quads>=2. Net per-lane A-granule = standard 32ch+8quad+j.
// K/V tiles double-buffered. Scalar deferred lsum. 8 waves x 16 q-rows.
// ---------------------------------------------------------------------------
__global__ __launch_bounds__(512)
void attn(const bf16* __restrict__ qg, const bf16* __restrict__ kg,
          const bf16* __restrict__ vtg, const float* __restrict__ mask,
          float* __restrict__ out) {
  const int blk = blockIdx.x;                // 0..511
  const int xcd = blk & 7, slot = blk >> 3;  // slot 0..63
  const int bh = xcd * 4 + (slot >> 4);      // 4 bh per XCD
  const int qblk = slot & 15;
  const int b = bh >> 4, h = bh & 15;
  const int tid = threadIdx.x;
  const int wave = tid >> 6, lane = tid & 63, quad = lane >> 4, c = lane & 15;
  const int lrow = lane >> 3, lg = (lane & 7) ^ lrow;

  __shared__ bf16 Ks[2][64 * 64];    // [key][d], swizzled granules
  __shared__ bf16 Vs[2][64 * 64];    // [d][key], swizzled granules

  const bf16* qb_ = qg + (size_t)bh * 2048 * 64;
  const bf16* kb_ = kg + (size_t)bh * 2048 * 64;
  const bf16* vb_ = vtg + (size_t)bh * 64 * 2048;
  const float* mk_ = mask + (size_t)b * 2048;

  bf16x8 qf[2];   // Q (pre-scaled by 0.125*log2e): row=c, k=ch*32+quad*8+j
  #pragma unroll
  for (int ch = 0; ch < 2; ++ch)
    qf[ch] = *(const bf16x8*)(qb_ +
        (size_t)(qblk * 128 + wave * 16 + c) * 64 + ch * 32 + quad * 8);

  // bpermute byte-indices: tc-even pulls qs=2(quad&1)+(quad>>1); tc-odd ^1
  const int idx0 = ((2 * (quad & 1) + (quad >> 1)) * 16 + c) << 2;
  const int idx1 = idx0 ^ 64;
  const bool qhi = (quad >= 2);
  const bool qodd = (quad & 1);

  f32x4 o[4] = {};
  float lsum = 0.f;

  {  // prologue: stage tile 0
    int r = wave * 8;
    stage16(kb_ + (size_t)(r + lrow) * 64 + lg * 8, &Ks[0][r * 64]);
    stage16(vb_ + (size_t)(r + lrow) * 2048 + lg * 8, &Vs[0][r * 64]);
  }

  for (int kt = 0; kt < 32; ++kt) {
    __syncthreads();             // tile kt staged; prev compute done
    const int cur = kt & 1;
    if (kt < 31) {               // stage kt+1 into the other half
      int r = wave * 8;
      stage16(kb_ + (size_t)((kt + 1) * 64 + r + lrow) * 64 + lg * 8,
              &Ks[cur ^ 1][r * 64]);
      stage16(vb_ + (size_t)(r + lrow) * 2048 + (kt + 1) * 64 + lg * 8,
              &Vs[cur ^ 1][r * 64]);
    }

    // ---- S^T = K Q^T: row=key(nt*16+4*quad+reg), col=qrow(c) ----
    f32x4 s[4] = {};
    #pragma unroll
    for (int nt = 0; nt < 4; ++nt)
      #pragma unroll
      for (int ch = 0; ch < 2; ++ch) {
        bf16x8 kf = *(const bf16x8*)&Ks[cur][(nt * 16 + c) * 64 +
                                            ((((ch << 2) | quad) ^ (c & 7)) << 3)];
        s[nt] = MFMA(kf, qf[ch], s[nt]);
      }

    // ---- p = exp2(s + mask[key]*log2e); pack bf16 pairs; scalar lsum ----
    int pk[4][2];
    #pragma unroll
    for (int nt = 0; nt < 4; ++nt) {
      float4 mv = *(const float4*)&mk_[kt * 64 + nt * 16 + 4 * quad];
      float mvf[4] = {mv.x, mv.y, mv.z, mv.w};
      float p[4];
      #pragma unroll
      for (int reg = 0; reg < 4; ++reg) {
        p[reg] = __builtin_amdgcn_exp2f(fmaf(mvf[reg], LOG2E, s[nt][reg]));
        lsum += p[reg];
      }
      pk[nt][0] = pk2(p[0], p[1]);
      pk[nt][1] = pk2(p[2], p[3]);
    }

    // ---- P^T(C-layout) -> P(A-layout), conflict-free schedule; O += P V ----
    #pragma unroll
    for (int ch = 0; ch < 2; ++ch) {
      const int tA = 2 * ch, tB = 2 * ch + 1;
      // every lane offers pk[tc ^ (own quad&1)][tp]
      int sA0 = qodd ? pk[tB][0] : pk[tA][0];
      int sA1 = qodd ? pk[tB][1] : pk[tA][1];
      int sB0 = qodd ? pk[tA][0] : pk[tB][0];
      int sB1 = qodd ? pk[tA][1] : pk[tB][1];
      int rA0 = __builtin_amdgcn_ds_bpermute(idx0, sA0);  // tc even
      int rA1 = __builtin_amdgcn_ds_bpermute(idx0, sA1);
      int rB0 = __builtin_amdgcn_ds_bpermute(idx1, sB0);  // tc odd
      int rB1 = __builtin_amdgcn_ds_bpermute(idx1, sB1);
      union { int i[4]; bf16x8 v; } pa;
      pa.i[0] = qhi ? rB0 : rA0;   // keys 32ch+8quad+{0,1}
      pa.i[1] = qhi ? rB1 : rA1;   //               +{2,3}
      pa.i[2] = qhi ? rA0 : rB0;   //               +{4,5}
      pa.i[3] = qhi ? rA1 : rB1;   //               +{6,7}
      #pragma unroll
      for (int nt = 0; nt < 4; ++nt) {
        bf16x8 vf = *(const bf16x8*)&Vs[cur][(nt * 16 + c) * 64 +
                                            ((((ch << 2) | quad) ^ (c & 7)) << 3)];
        o[nt] = MFMA(pa.v, vf, o[nt]);
      }
    }
  }

  // ---- l: reduce over quads (same c), route to O's row indexing ----
  lsum += __shfl_xor(lsum, 16, 64);
  lsum += __shfl_xor(lsum, 32, 64);
  #pragma unroll
  for (int reg = 0; reg < 4; ++reg) {
    float inv = 1.0f / __shfl(lsum, 4 * quad + reg, 64);  // l for qrow=4*quad+reg
    int srow = qblk * 128 + wave * 16 + 4 * quad + reg;
    #pragma unroll
    for (int nt = 0; nt < 4; ++nt)
      out[((size_t)b * 2048 + srow) * 1024 + h * 64 + nt * 16 + c] =
          o[nt][reg] * inv;
  }
}

// ---------------------------------------------------------------------------
extern "C" void kernel_launch(void* const* d_in, const int* in_sizes, int n_in,
                              void* d_out, int out_size, void* d_ws, size_t ws_size,
                              hipStream_t stream) {
  const float* hs   = (const float*)d_in[0];
  const float* mask = (const float*)d_in[1];
  const float* qw   = (const float*)d_in[2];
  const float* qb   = (const float*)d_in[3];
  const float* kw   = (const float*)d_in[4];
  const float* kb   = (const float*)d_in[5];
  const float* vw   = (const float*)d_in[6];
  const float* vb   = (const float*)d_in[7];
  float* out = (float*)d_out;

  bf16* Xb   = (bf16*)d_ws;                       // 4096x1024      (8 MB)
  bf16* Wt   = Xb + (size_t)4096 * 1024;          // 3x1024x1024    (6 MB)
  bf16* q_ws = Wt + (size_t)3 * 1048576;          // [B,H,S,64]     (8 MB)
  bf16* k_ws = q_ws + (size_t)4096 * 1024;        // [B,H,S,64]     (8 MB)
  bf16* v_ws = k_ws + (size_t)4096 * 1024;        // [B,H,64,S] V^T (8 MB)

  cvt<<<dim3(2816), 256, 0, stream>>>(hs, qw, kw, vw, Xb, Wt);
  qkv_gemm<<<dim3(768), 256, 0, stream>>>(Xb, Wt, qb, kb, vb, q_ws, k_ws, v_ws);
  attn<<<dim3(512), 512, 0, stream>>>(q_ws, k_ws, v_ws, mask, out);
}

// Round 6
// 180.360 us; speedup vs baseline: 1.0869x; 1.0869x over previous
//
#include <hip/hip_runtime.h>

typedef __bf16 bf16;
typedef __attribute__((ext_vector_type(8))) __bf16 bf16x8;
typedef __attribute__((ext_vector_type(4))) __bf16 bf16x4;
typedef __attribute__((ext_vector_type(4))) float f32x4;

#define MFMA(a, b, c) __builtin_amdgcn_mfma_f32_16x16x32_bf16((a), (b), (c), 0, 0, 0)
#define LOG2E 1.44269504088896340736f

__device__ __forceinline__ bf16x8 cvt8(float4 a, float4 b) {
  bf16x8 r;
  r[0] = (bf16)a.x; r[1] = (bf16)a.y; r[2] = (bf16)a.z; r[3] = (bf16)a.w;
  r[4] = (bf16)b.x; r[5] = (bf16)b.y; r[6] = (bf16)b.z; r[7] = (bf16)b.w;
  return r;
}

// async global->LDS, 16B per lane. LDS dest = wave-uniform base + lane*16.
__device__ __forceinline__ void stage16(const bf16* g, bf16* l) {
  __builtin_amdgcn_global_load_lds(
      (const __attribute__((address_space(1))) void*)g,
      (__attribute__((address_space(3))) void*)l, 16, 0, 0);
}

// ---------------------------------------------------------------------------
// Kernel 0: cast X -> bf16; cast+transpose W -> bf16 W^T[n][k] (3 matrices).
// ---------------------------------------------------------------------------
__global__ __launch_bounds__(256)
void cvt(const float* __restrict__ hs, const float* __restrict__ qw,
         const float* __restrict__ kw, const float* __restrict__ vw,
         bf16* __restrict__ Xb, bf16* __restrict__ Wt) {
  const int bid = blockIdx.x, tid = threadIdx.x;
  if (bid < 2048) {               // X: 4096x1024 fp32 -> bf16, 8 elems/thread
    size_t off = (size_t)bid * 2048 + tid * 8;
    float4 x0 = *(const float4*)(hs + off);
    float4 x1 = *(const float4*)(hs + off + 4);
    *(bf16x8*)(Xb + off) = cvt8(x0, x1);
  } else {                        // W transpose: 64x64 tiles via LDS
    int t = bid - 2048;           // 0..767
    int z = t >> 8, ti = t & 255;
    const float* W = (z == 0) ? qw : (z == 1) ? kw : vw;
    int k0 = (ti >> 4) * 64, n0 = (ti & 15) * 64;
    __shared__ bf16 T[64 * 72];   // [n][k], pad 72
    #pragma unroll
    for (int i = 0; i < 16; ++i) {
      int e = i * 256 + tid;
      int kr = e >> 6, nc = e & 63;
      T[nc * 72 + kr] = (bf16)W[(size_t)(k0 + kr) * 1024 + n0 + nc];
    }
    __syncthreads();
    #pragma unroll
    for (int i = 0; i < 2; ++i) {
      int e = i * 256 + tid;
      int nr = e >> 3, kg = e & 7;
      *(bf16x8*)(Wt + (size_t)z * 1048576 + (size_t)(n0 + nr) * 1024 + k0 + kg * 8) =
          *(const bf16x8*)&T[nr * 72 + kg * 8];
    }
  }
}

// ---------------------------------------------------------------------------
// Kernel 1: QKV GEMM — m97 shape: 128x128 tile, 4 waves 2x2, BK=32,
// global_load_lds w=16, granule-XOR swizzle on the global-address side.
// 768 blocks = one clean round at 3/CU. XCD swizzle: mb-band per XCD.
// Q pre-scaled by 0.125*log2e. V stored TRANSPOSED [B,H,64,S].
// ---------------------------------------------------------------------------
__global__ __launch_bounds__(256, 3)
void qkv_gemm(const bf16* __restrict__ Xb, const bf16* __restrict__ Wt,
              const float* __restrict__ qbias, const float* __restrict__ kbias,
              const float* __restrict__ vbias,
              bf16* __restrict__ qo, bf16* __restrict__ ko, bf16* __restrict__ vo) {
  const int blk = blockIdx.x;                 // 0..767
  const int xcd = blk & 7, slot = blk >> 3;   // slot 0..95
  const int mb = xcd * 4 + slot / 24;         // 0..31
  const int nb = slot % 24;                   // 0..23
  const int z = nb >> 3, nbm = nb & 7;
  const bf16* W = Wt + (size_t)z * 1048576;

  const int tid = threadIdx.x;
  const int wave = tid >> 6, lane = tid & 63, quad = lane >> 4, c = lane & 15;
  const int wr = wave >> 1, wc = wave & 1;
  const int r4 = lane >> 2;                   // 0..15: row within 16-row group
  const int g4 = (lane & 3) ^ (r4 & 3);       // swizzled source granule (4/row)

  __shared__ bf16 As[128 * 32];               // [m][k], granule g stored at g^(m&3)
  __shared__ bf16 Bs[128 * 32];               // [n][k], same swizzle

  const bf16* aS0 = Xb + (size_t)(mb * 128 + wave * 16 + r4) * 1024 + g4 * 8;
  const bf16* aS1 = aS0 + (size_t)64 * 1024;
  const bf16* bS0 = W + (size_t)(nbm * 128 + wave * 16 + r4) * 1024 + g4 * 8;
  const bf16* bS1 = bS0 + (size_t)64 * 1024;
  bf16* aD0 = &As[(wave * 16) * 32];
  bf16* aD1 = &As[(64 + wave * 16) * 32];
  bf16* bD0 = &Bs[(wave * 16) * 32];
  bf16* bD1 = &Bs[(64 + wave * 16) * 32];

  int aOff[4], bOff[4];
  #pragma unroll
  for (int t = 0; t < 4; ++t) {
    aOff[t] = (wr * 64 + t * 16 + c) * 32 + ((quad ^ (c & 3)) << 3);
    bOff[t] = (wc * 64 + t * 16 + c) * 32 + ((quad ^ (c & 3)) << 3);
  }

  f32x4 acc[4][4] = {};

  for (int k0 = 0; k0 < 1024; k0 += 32) {
    stage16(aS0 + k0, aD0);
    stage16(aS1 + k0, aD1);
    stage16(bS0 + k0, bD0);
    stage16(bS1 + k0, bD1);
    __syncthreads();
    bf16x8 af[4];
    #pragma unroll
    for (int rt = 0; rt < 4; ++rt) af[rt] = *(const bf16x8*)&As[aOff[rt]];
    #pragma unroll
    for (int nt = 0; nt < 4; ++nt) {
      bf16x8 bfrag = *(const bf16x8*)&Bs[bOff[nt]];
      #pragma unroll
      for (int rt = 0; rt < 4; ++rt)
        acc[rt][nt] = MFMA(af[rt], bfrag, acc[rt][nt]);
    }
    __syncthreads();
  }

  const float* bias = (z == 0) ? qbias : (z == 1) ? kbias : vbias;
  float bv[4];
  #pragma unroll
  for (int nt = 0; nt < 4; ++nt)
    bv[nt] = bias[nbm * 128 + wc * 64 + nt * 16 + c];

  if (z == 2) {
    // V^T: vo[((b*16+h)*64 + d)*2048 + s], packed 4 along s (= reg dim)
    #pragma unroll
    for (int rt = 0; rt < 4; ++rt)
      #pragma unroll
      for (int nt = 0; nt < 4; ++nt) {
        int m0 = mb * 128 + wr * 64 + rt * 16 + 4 * quad;
        int n = nbm * 128 + wc * 64 + nt * 16 + c;
        bf16x4 pk;
        #pragma unroll
        for (int reg = 0; reg < 4; ++reg) pk[reg] = (bf16)(acc[rt][nt][reg] + bv[nt]);
        int b = m0 >> 11, s0 = m0 & 2047, h = n >> 6, d = n & 63;
        *(bf16x4*)&vo[(((size_t)b * 16 + h) * 64 + d) * 2048 + s0] = pk;
      }
  } else {
    bf16* dst = (z == 0) ? qo : ko;
    const float scale = (z == 0) ? 0.125f * LOG2E : 1.0f;
    #pragma unroll
    for (int rt = 0; rt < 4; ++rt)
      #pragma unroll
      for (int nt = 0; nt < 4; ++nt)
        #pragma unroll
        for (int reg = 0; reg < 4; ++reg) {
          float v = (acc[rt][nt][reg] + bv[nt]) * scale;
          int m = mb * 128 + wr * 64 + rt * 16 + 4 * quad + reg;
          int n = nbm * 128 + wc * 64 + nt * 16 + c;
          int b = m >> 11, s = m & 2047, h = n >> 6, d = n & 63;
          dst[(((size_t)b * 16 + h) * 2048 + s) * 64 + d] = (bf16)v;
        }
  }
}

// ---------------------------------------------------------------------------
// Kernel 2: attention — R3's verified structure (S direct, P LDS round-trip,
// 0 bank conflicts), re-partitioned: 256 threads (4 waves x 16 q-rows =
// 64 q-rows/WG), 1024 WGs -> 4 independent barrier-groups per CU (was 2)
// so __syncthreads/vmcnt drains of one block overlap compute of others.
// LDS 24 KB/block. XCD swizzle: each (b,h)'s K/V pinned to one XCD's L2.
// ---------------------------------------------------------------------------
__global__ __launch_bounds__(256, 4)
void attn(const bf16* __restrict__ qg, const bf16* __restrict__ kg,
          const bf16* __restrict__ vtg, const float* __restrict__ mask,
          float* __restrict__ out) {
  const int blk = blockIdx.x;                // 0..1023
  const int xcd = blk & 7, slot = blk >> 3;  // slot 0..127
  const int bh = xcd * 4 + (slot >> 5);      // 4 bh per XCD
  const int qblk = slot & 31;                // 0..31, 64 q-rows each
  const int b = bh >> 4, h = bh & 15;
  const int tid = threadIdx.x;
  const int wave = tid >> 6, lane = tid & 63, quad = lane >> 4, c = lane & 15;
  const int lrow = lane >> 3, lg = (lane & 7) ^ lrow;

  __shared__ bf16 Ks[64 * 64];    // [key][d], swizzled granules
  __shared__ bf16 Vs[64 * 64];    // [d][key], swizzled granules
  __shared__ bf16 Ps[4][1024];    // per-wave P: 16 rows x 64 keys, swizzled

  const bf16* qb_ = qg + (size_t)bh * 2048 * 64;
  const bf16* kb_ = kg + (size_t)bh * 2048 * 64;
  const bf16* vb_ = vtg + (size_t)bh * 64 * 2048;

  bf16x8 qf[2];   // Q pre-scaled by 0.125*log2e; wave owns rows wave*16..+15
  #pragma unroll
  for (int ch = 0; ch < 2; ++ch)
    qf[ch] = *(const bf16x8*)(qb_ +
        (size_t)(qblk * 64 + wave * 16 + c) * 64 + ch * 32 + quad * 8);

  f32x4 o[4] = {};
  float lsum[4] = {};

  for (int kt = 0; kt < 32; ++kt) {
    #pragma unroll
    for (int i = 0; i < 2; ++i) {  // stage K [64 keys][64 d], V [64 d][64 keys]
      int r = wave * 16 + i * 8;
      stage16(kb_ + (size_t)(kt * 64 + r + lrow) * 64 + lg * 8, &Ks[r * 64]);
      stage16(vb_ + (size_t)(r + lrow) * 2048 + kt * 64 + lg * 8, &Vs[r * 64]);
    }
    __syncthreads();

    // ---- S = Q K^T (log2-domain scale already in Q) ----
    f32x4 s[4] = {};
    #pragma unroll
    for (int nt = 0; nt < 4; ++nt)
      #pragma unroll
      for (int ch = 0; ch < 2; ++ch) {
        bf16x8 kf = *(const bf16x8*)&Ks[(nt * 16 + c) * 64 +
                                        ((((ch << 2) | quad) ^ (c & 7)) << 3)];
        s[nt] = MFMA(qf[ch], kf, s[nt]);
      }

    float mv[4];
    #pragma unroll
    for (int nt = 0; nt < 4; ++nt)
      mv[nt] = mask[b * 2048 + kt * 64 + nt * 16 + c] * LOG2E;

    // ---- p = exp2(s + mask), per-lane l, spill P to LDS (wave-private) ----
    #pragma unroll
    for (int nt = 0; nt < 4; ++nt)
      #pragma unroll
      for (int reg = 0; reg < 4; ++reg) {
        float p = __builtin_amdgcn_exp2f(s[nt][reg] + mv[nt]);
        lsum[reg] += p;
        int r = 4 * quad + reg;
        int gk = nt * 2 + (c >> 3);
        Ps[wave][r * 64 + ((gk ^ (r & 7)) << 3) + (c & 7)] = (bf16)p;
      }
    __asm__ volatile("s_waitcnt lgkmcnt(0)" ::: "memory");  // order write->read

    // ---- O += P V ----
    #pragma unroll
    for (int ch = 0; ch < 2; ++ch) {
      bf16x8 pa = *(const bf16x8*)&Ps[wave][c * 64 +
                                           ((((ch << 2) | quad) ^ (c & 7)) << 3)];
      #pragma unroll
      for (int nt = 0; nt < 4; ++nt) {
        bf16x8 vf = *(const bf16x8*)&Vs[(nt * 16 + c) * 64 +
                                        ((((ch << 2) | quad) ^ (c & 7)) << 3)];
        o[nt] = MFMA(pa, vf, o[nt]);
      }
    }
    __syncthreads();
  }

  // ---- final l reduction (16 lanes of the quad) + normalize + store ----
  #pragma unroll
  for (int reg = 0; reg < 4; ++reg) {
    float l = lsum[reg];
    #pragma unroll
    for (int off = 1; off < 16; off <<= 1) l += __shfl_xor(l, off, 64);
    float inv = 1.0f / l;
    int srow = qblk * 64 + wave * 16 + 4 * quad + reg;
    #pragma unroll
    for (int nt = 0; nt < 4; ++nt)
      out[((size_t)b * 2048 + srow) * 1024 + h * 64 + nt * 16 + c] =
          o[nt][reg] * inv;
  }
}

// ---------------------------------------------------------------------------
extern "C" void kernel_launch(void* const* d_in, const int* in_sizes, int n_in,
                              void* d_out, int out_size, void* d_ws, size_t ws_size,
                              hipStream_t stream) {
  const float* hs   = (const float*)d_in[0];
  const float* mask = (const float*)d_in[1];
  const float* qw   = (const float*)d_in[2];
  const float* qb   = (const float*)d_in[3];
  const float* kw   = (const float*)d_in[4];
  const float* kb   = (const float*)d_in[5];
  const float* vw   = (const float*)d_in[6];
  const float* vb   = (const float*)d_in[7];
  float* out = (float*)d_out;

  bf16* Xb   = (bf16*)d_ws;                       // 4096x1024      (8 MB)
  bf16* Wt   = Xb + (size_t)4096 * 1024;          // 3x1024x1024    (6 MB)
  bf16* q_ws = Wt + (size_t)3 * 1048576;          // [B,H,S,64]     (8 MB)
  bf16* k_ws = q_ws + (size_t)4096 * 1024;        // [B,H,S,64]     (8 MB)
  bf16* v_ws = k_ws + (size_t)4096 * 1024;        // [B,H,64,S] V^T (8 MB)

  cvt<<<dim3(2816), 256, 0, stream>>>(hs, qw, kw, vw, Xb, Wt);
  qkv_gemm<<<dim3(768), 256, 0, stream>>>(Xb, Wt, qb, kb, vb, q_ws, k_ws, v_ws);
  attn<<<dim3(1024), 256, 0, stream>>>(q_ws, k_ws, v_ws, mask, out);
}